// Round 1
// baseline (349.761 us; speedup 1.0000x reference)
//
#include <hip/hip_runtime.h>
#include <math.h>

// ---- marching-tets tables ----
__constant__ int c_tri_table[16][6] = {
    {-1,-1,-1,-1,-1,-1},{1,0,2,-1,-1,-1},{4,0,3,-1,-1,-1},{1,4,2,1,3,4},
    {3,1,5,-1,-1,-1},{2,3,0,2,5,3},{1,4,0,1,5,4},{4,2,5,-1,-1,-1},
    {4,5,2,-1,-1,-1},{4,1,0,4,5,1},{3,2,0,3,5,2},{1,3,5,-1,-1,-1},
    {4,1,2,4,3,1},{3,0,4,-1,-1,-1},{2,0,1,-1,-1,-1},{-1,-1,-1,-1,-1,-1}};
__constant__ int c_num_tri[16] = {0,1,1,2,1,2,2,1,1,2,2,1,2,1,1,0};

// Per-unique-edge vertex interpolation.
__global__ void dmtet_verts_kernel(const float* __restrict__ pos,
                                   const float* __restrict__ sdf,
                                   const int2* __restrict__ edges,
                                   float* __restrict__ verts, int Eu) {
    int stride = gridDim.x * blockDim.x;
    for (int e = blockIdx.x * blockDim.x + threadIdx.x; e < Eu; e += stride) {
        int2 ed = edges[e];
        float s0 = sdf[ed.x];
        float s1 = sdf[ed.y];
        bool crossing = (s0 > 0.0f) != (s1 > 0.0f);
        float denom = crossing ? (s0 - s1) : 1.0f;
        float w0 = -s1 / denom;
        float w1 =  s0 / denom;
        const float* p0 = pos + 3LL * ed.x;
        const float* p1 = pos + 3LL * ed.y;
        float ox = crossing ? (p0[0] * w0 + p1[0] * w1) : 0.0f;
        float oy = crossing ? (p0[1] * w0 + p1[1] * w1) : 0.0f;
        float oz = crossing ? (p0[2] * w0 + p1[2] * w1) : 0.0f;
        long long o = 3LL * e;
        verts[o + 0] = ox;
        verts[o + 1] = oy;
        verts[o + 2] = oz;
    }
}

// Per-tet: faces (T,2,3) and uv_idx (T,2,3), both written as float32.
__global__ void dmtet_tets_kernel(const float* __restrict__ sdf,
                                  const int4* __restrict__ tets,
                                  const int2* __restrict__ idx_map, // 3 int2 per tet row
                                  float* __restrict__ faces_out,
                                  float* __restrict__ uvidx_out, int T) {
    int stride = gridDim.x * blockDim.x;
    for (int t = blockIdx.x * blockDim.x + threadIdx.x; t < T; t += stride) {
        int4 v = tets[t];
        int idx = (sdf[v.x] > 0.0f ? 1 : 0) | (sdf[v.y] > 0.0f ? 2 : 0) |
                  (sdf[v.z] > 0.0f ? 4 : 0) | (sdf[v.w] > 0.0f ? 8 : 0);
        int  ntri  = c_num_tri[idx];
        bool valid = (idx != 0) && (idx != 15);

        int2 a = idx_map[3LL * t + 0];
        int2 b = idx_map[3LL * t + 1];
        int2 c = idx_map[3LL * t + 2];
        int im[6] = {a.x, a.y, b.x, b.y, c.x, c.y};

        long long o = 6LL * t;
        #pragma unroll
        for (int j = 0; j < 6; ++j) {
            bool tv = valid && ((j < 3) ? (ntri > 0) : (ntri > 1));
            int tri = c_tri_table[idx][j];
            int cl = tri < 0 ? 0 : tri;          // clip(tri, 0, 5)
            faces_out[o + j] = (float)(tv ? im[cl] : -1);
        }

        int base = 4 * t;   // tet_idx == t since T == Ngrid*Ngrid here
        bool tv0 = valid && (ntri > 0);
        bool tv1 = valid && (ntri > 1);
        uvidx_out[o + 0] = tv0 ? (float)(base)     : -1.0f;
        uvidx_out[o + 1] = tv0 ? (float)(base + 1) : -1.0f;
        uvidx_out[o + 2] = tv0 ? (float)(base + 2) : -1.0f;
        uvidx_out[o + 3] = tv1 ? (float)(base)     : -1.0f;
        uvidx_out[o + 4] = tv1 ? (float)(base + 2) : -1.0f;
        uvidx_out[o + 5] = tv1 ? (float)(base + 3) : -1.0f;
    }
}

// UV atlas fill: (Ngrid*Ngrid*4) float2 entries.
__global__ void dmtet_uvs_kernel(float2* __restrict__ uvs, int Ngrid,
                                 int total, float step, float pad) {
    int stride = gridDim.x * blockDim.x;
    for (int k = blockIdx.x * blockDim.x + threadIdx.x; k < total; k += stride) {
        int q = k >> 2;      // quad id
        int j = k & 3;       // corner id
        int gx = q % Ngrid;
        int gy = q / Ngrid;
        float x = (float)gx * step;
        float y = (float)gy * step;
        float u = (j == 1 || j == 2) ? x + pad : x;
        float w = (j >= 2) ? y + pad : y;
        uvs[k] = make_float2(u, w);
    }
}

extern "C" void kernel_launch(void* const* d_in, const int* in_sizes, int n_in,
                              void* d_out, int out_size, void* d_ws, size_t ws_size,
                              hipStream_t stream) {
    const float* pos     = (const float*)d_in[0];
    const float* sdf     = (const float*)d_in[1];
    const int*   tet     = (const int*)d_in[2];
    const int*   edges   = (const int*)d_in[3];
    const int*   idx_map = (const int*)d_in[4];

    int T  = in_sizes[2] / 4;
    int Eu = in_sizes[3] / 2;

    long long half = (2LL * T + 1) / 2;
    int Ngrid = (int)ceil(sqrt((double)half));
    while ((long long)Ngrid * Ngrid < half) Ngrid++;            // safety
    while ((long long)(Ngrid - 1) * (Ngrid - 1) >= half) Ngrid--;

    float* out   = (float*)d_out;
    float* verts = out;
    float* faces = verts + 3LL * Eu;
    float* uvs   = faces + 6LL * T;
    float* uvidx = uvs   + 8LL * Ngrid * Ngrid;

    float step = (float)((1.0 - 1.0 / (double)Ngrid) / (double)(Ngrid - 1));
    float pad  = 0.9f / (float)Ngrid;

    const int BLK = 256;
    auto nblk = [&](long long n) {
        long long b = (n + BLK - 1) / BLK;
        return (int)(b > 16384 ? 16384 : b);
    };

    dmtet_verts_kernel<<<nblk(Eu), BLK, 0, stream>>>(
        pos, sdf, (const int2*)edges, verts, Eu);

    dmtet_tets_kernel<<<nblk(T), BLK, 0, stream>>>(
        sdf, (const int4*)tet, (const int2*)idx_map, faces, uvidx, T);

    int total_uv = Ngrid * Ngrid * 4;
    dmtet_uvs_kernel<<<nblk(total_uv), BLK, 0, stream>>>(
        (float2*)uvs, Ngrid, total_uv, step, pad);
}